// Round 3
// baseline (3972.423 us; speedup 1.0000x reference)
//
#include <hip/hip_runtime.h>

#ifndef __has_builtin
#define __has_builtin(x) 0
#endif

__device__ __forceinline__ float fexp2(float x) {
#if __has_builtin(__builtin_amdgcn_exp2f)
  return __builtin_amdgcn_exp2f(x);   // v_exp_f32 (2^x)
#else
  return exp2f(x);
#endif
}
__device__ __forceinline__ float flog2(float x) {
#if __has_builtin(__builtin_amdgcn_logf)
  return __builtin_amdgcn_logf(x);    // v_log_f32 (log2)
#else
  return log2f(x);
#endif
}

namespace {
constexpr int NPTS = 2048;
constexpr int NPROB = 24;          // 8 batches x {xy, xx, yy}
constexpr int WGS_PER_PROB = 32;   // 64 rows per WG -> grid 768 = 3 WG/CU
constexpr int THREADS = 256;       // 16 row-groups x 16 source-chunks
constexpr int CHUNKS = 16;
constexpr int RPT = 4;             // rows per thread (register tile)
constexpr int NPASS = 100;         // 50 Sinkhorn iters x 2 half-passes
constexpr int BARSTRIDE = 16;      // one 64B cacheline per problem counter
constexpr float LOG2E = 1.44269504088896340736f;
constexpr float KS = LOG2E / 0.0025f;                  // log2(e)/eps
constexpr float NEG_EPS_LN2 = -0.0025f * 0.69314718055994530942f; // -eps*ln2
constexpr float LOG2N = 11.0f;                         // log2(2048)
}

// Zero the per-problem barrier counters (ws is poisoned 0xAA each call).
__global__ void sink_init(unsigned* __restrict__ bar) {
  int i = threadIdx.x;
  if (i < NPROB * BARSTRIDE) bar[i] = 0u;
}

// Persistent kernel: all 100 Sinkhorn half-passes in one cooperative launch.
// Per pass, for each target row i:
//   out_i = -eps*( ln(sum_j exp((phi_j - C_ij)/eps)) - ln(2048) )
// base-2: w_ij = KS*t_i.s_j + A_j (+ Bi folded at the end),
//   A_j = KS*phi_j - 0.5*KS*|s_j|^2, Bi = -0.5*KS*|t_i|^2.
// Cross-WG phi traffic uses agent-scope relaxed atomics (per-XCD L2s are not
// coherent); a per-problem 32-WG counter barrier (release add / acquire spin)
// separates passes.
__global__ void __launch_bounds__(THREADS) sink_persist(
    const float* __restrict__ p1, const float* __restrict__ p2,
    float* __restrict__ fpot, float* __restrict__ gpot,
    unsigned* __restrict__ bar)
{
  __shared__ float4 Ls[NPTS];   // (KS*sx, KS*sy, KS*sz, A_j)

  const int w   = blockIdx.x;
  const int p   = w >> 5;          // problem 0..23
  const int blk = w & 31;          // row-block within problem
  const int b    = p / 3;
  const int kind = p - 3 * b;      // 0: xy, 1: xx, 2: yy
  const float* X = (kind == 2 ? p2 : p1) + b * (NPTS * 3);
  const float* Y = (kind == 1 ? p1 : p2) + b * (NPTS * 3);

  const int tid = threadIdx.x;
  const int c  = tid & (CHUNKS - 1);       // source chunk
  const int rg = tid >> 4;                 // row group 0..15
  const int row0 = blk * 64 + rg * RPT;
  unsigned* cnt = bar + p * BARSTRIDE;

  for (int t = 0; t < NPASS; ++t) {
    const bool even = (t & 1) == 0;
    const float* tgt = even ? X : Y;       // even: f-update (rows of X)
    const float* src = even ? Y : X;
    const float* phi = (even ? gpot : fpot) + p * NPTS;
    float*      outp = (even ? fpot : gpot) + p * NPTS;

    // ---- stage prescaled source data into LDS ----
    #pragma unroll
    for (int i = 0; i < NPTS / THREADS; ++i) {
      int j = tid + THREADS * i;
      float sx = src[3 * j + 0], sy = src[3 * j + 1], sz = src[3 * j + 2];
      float ph = (t == 0) ? 0.0f
          : __hip_atomic_load(&phi[j], __ATOMIC_RELAXED, __HIP_MEMORY_SCOPE_AGENT);
      float A = fmaf(KS, ph, -0.5f * KS * (sx * sx + sy * sy + sz * sz));
      Ls[j] = make_float4(KS * sx, KS * sy, KS * sz, A);
    }

    // ---- per-thread target rows (constant input data; plain loads ok) ----
    float tx0 = tgt[3 * (row0 + 0) + 0], ty0 = tgt[3 * (row0 + 0) + 1], tz0 = tgt[3 * (row0 + 0) + 2];
    float tx1 = tgt[3 * (row0 + 1) + 0], ty1 = tgt[3 * (row0 + 1) + 1], tz1 = tgt[3 * (row0 + 1) + 2];
    float tx2 = tgt[3 * (row0 + 2) + 0], ty2 = tgt[3 * (row0 + 2) + 1], tz2 = tgt[3 * (row0 + 2) + 2];
    float tx3 = tgt[3 * (row0 + 3) + 0], ty3 = tgt[3 * (row0 + 3) + 1], tz3 = tgt[3 * (row0 + 3) + 2];
    __syncthreads();

    float mb0 = -1e30f, mb1 = -1e30f, mb2 = -1e30f, mb3 = -1e30f;
    float s0 = 0.f, s1 = 0.f, s2 = 0.f, s3 = 0.f;
    const float4* Lp = Ls + c;

    // Quad-of-sources online LSE for one row
#define QSTEP(tx, ty, tz, mb, ss) {                                          \
    float u0_ = fmaf(tx, L0.x, fmaf(ty, L0.y, fmaf(tz, L0.z, L0.w)));        \
    float u1_ = fmaf(tx, L1.x, fmaf(ty, L1.y, fmaf(tz, L1.z, L1.w)));        \
    float u2_ = fmaf(tx, L2.x, fmaf(ty, L2.y, fmaf(tz, L2.z, L2.w)));        \
    float u3_ = fmaf(tx, L3.x, fmaf(ty, L3.y, fmaf(tz, L3.z, L3.w)));        \
    float m_  = fmaxf(fmaxf(u0_, u1_), fmaxf(u2_, u3_));                     \
    float es_ = (fexp2(u0_ - m_) + fexp2(u1_ - m_))                          \
              + (fexp2(u2_ - m_) + fexp2(u3_ - m_));                         \
    float mo_ = fmaxf(mb, m_);                                               \
    (ss) = fmaf((ss), fexp2((mb) - mo_), es_ * fexp2(m_ - mo_));             \
    (mb) = mo_; }

    #pragma unroll 2
    for (int q = 0; q < NPTS / (CHUNKS * 4); ++q) {
      const float4* Lq = Lp + 64 * q;     // j = 16*(4q+k) + c
      float4 L0 = Lq[0];
      float4 L1 = Lq[16];
      float4 L2 = Lq[32];
      float4 L3 = Lq[48];
      QSTEP(tx0, ty0, tz0, mb0, s0);
      QSTEP(tx1, ty1, tz1, mb1, s1);
      QSTEP(tx2, ty2, tz2, mb2, s2);
      QSTEP(tx3, ty3, tz3, mb3, s3);
    }
#undef QSTEP

    // ---- merge the 16 chunk lanes (butterfly within 16-lane groups) ----
#define LMERGE(mb, ss) {                                                     \
    float Mo_ = __shfl_xor((mb), off);                                       \
    float So_ = __shfl_xor((ss), off);                                       \
    float mo_ = fmaxf((mb), Mo_);                                            \
    (ss) = fmaf((ss), fexp2((mb) - mo_), So_ * fexp2(Mo_ - mo_));            \
    (mb) = mo_; }

    #pragma unroll
    for (int off = 1; off <= 8; off <<= 1) {
      LMERGE(mb0, s0);
      LMERGE(mb1, s1);
      LMERGE(mb2, s2);
      LMERGE(mb3, s3);
    }
#undef LMERGE

    if (c == 0) {
      float B0 = -0.5f * KS * (tx0 * tx0 + ty0 * ty0 + tz0 * tz0);
      float B1 = -0.5f * KS * (tx1 * tx1 + ty1 * ty1 + tz1 * tz1);
      float B2 = -0.5f * KS * (tx2 * tx2 + ty2 * ty2 + tz2 * tz2);
      float B3 = -0.5f * KS * (tx3 * tx3 + ty3 * ty3 + tz3 * tz3);
      float v0 = NEG_EPS_LN2 * (mb0 + B0 + flog2(s0) - LOG2N);
      float v1 = NEG_EPS_LN2 * (mb1 + B1 + flog2(s1) - LOG2N);
      float v2 = NEG_EPS_LN2 * (mb2 + B2 + flog2(s2) - LOG2N);
      float v3 = NEG_EPS_LN2 * (mb3 + B3 + flog2(s3) - LOG2N);
      __hip_atomic_store(&outp[row0 + 0], v0, __ATOMIC_RELAXED, __HIP_MEMORY_SCOPE_AGENT);
      __hip_atomic_store(&outp[row0 + 1], v1, __ATOMIC_RELAXED, __HIP_MEMORY_SCOPE_AGENT);
      __hip_atomic_store(&outp[row0 + 2], v2, __ATOMIC_RELAXED, __HIP_MEMORY_SCOPE_AGENT);
      __hip_atomic_store(&outp[row0 + 3], v3, __ATOMIC_RELAXED, __HIP_MEMORY_SCOPE_AGENT);
    }

    // ---- per-problem barrier: 32 WGs, release add + acquire spin ----
    if (t != NPASS - 1) {
      __syncthreads();   // all lanes' stores drained (vmcnt 0) before release
      if (tid == 0) {
        __hip_atomic_fetch_add(cnt, 1u, __ATOMIC_RELEASE, __HIP_MEMORY_SCOPE_AGENT);
        const unsigned target = (unsigned)(WGS_PER_PROB * (t + 1));
        while (__hip_atomic_load(cnt, __ATOMIC_ACQUIRE, __HIP_MEMORY_SCOPE_AGENT) < target)
          __builtin_amdgcn_s_sleep(1);
      }
      __syncthreads();
    }
  }
}

// Deterministic final reduction over the concatenated [fpot|gpot] array.
// weight(elem in problem p) = (p%3==0 ? 1 : -0.5), result /= 8*2048.
__global__ void __launch_bounds__(1024) sink_finalize(
    const float* __restrict__ pot, float* __restrict__ out)
{
  __shared__ double red[1024];
  const int tid = threadIdx.x;
  const float4* p4 = (const float4*)pot;
  const int TOT4 = 2 * NPROB * NPTS / 4;   // 24576, 512 float4 per 2048-block
  double acc = 0.0;
  for (int i = tid; i < TOT4; i += 1024) {
    int knd = (i >> 9) % 3;
    float4 v = p4[i];
    double s = ((double)v.x + (double)v.y) + ((double)v.z + (double)v.w);
    acc += (knd == 0) ? s : -0.5 * s;
  }
  red[tid] = acc;
  __syncthreads();
  for (int st = 512; st > 0; st >>= 1) {
    if (tid < st) red[tid] += red[tid + st];
    __syncthreads();
  }
  if (tid == 0) out[0] = (float)(red[0] / (8.0 * 2048.0));
}

extern "C" void kernel_launch(void* const* d_in, const int* in_sizes, int n_in,
                              void* d_out, int out_size, void* d_ws, size_t ws_size,
                              hipStream_t stream)
{
  const float* p1 = (const float*)d_in[0];   // pcs1 [8,2048,3] f32
  const float* p2 = (const float*)d_in[1];   // pcs2 [8,2048,3] f32
  float* fpot = (float*)d_ws;                // [24][2048]
  float* gpot = fpot + NPROB * NPTS;         // [24][2048]
  unsigned* bar = (unsigned*)(gpot + NPROB * NPTS);  // [24*16] counters

  sink_init<<<dim3(1), dim3(THREADS * 2), 0, stream>>>(bar);

  void* args[] = { (void*)&p1, (void*)&p2, (void*)&fpot, (void*)&gpot, (void*)&bar };
  hipLaunchCooperativeKernel((const void*)sink_persist,
                             dim3(NPROB * WGS_PER_PROB), dim3(THREADS),
                             args, 0, stream);

  sink_finalize<<<dim3(1), dim3(1024), 0, stream>>>(fpot, (float*)d_out);
}

// Round 6
// 3188.493 us; speedup vs baseline: 1.2459x; 1.2459x over previous
//
#include <hip/hip_runtime.h>

#ifndef __has_builtin
#define __has_builtin(x) 0
#endif

__device__ __forceinline__ float fexp2(float x) {
#if __has_builtin(__builtin_amdgcn_exp2f)
  return __builtin_amdgcn_exp2f(x);   // v_exp_f32 (2^x)
#else
  return exp2f(x);
#endif
}
__device__ __forceinline__ float flog2(float x) {
#if __has_builtin(__builtin_amdgcn_logf)
  return __builtin_amdgcn_logf(x);    // v_log_f32 (log2)
#else
  return log2f(x);
#endif
}

namespace {
constexpr int NPTS = 2048;
constexpr int NPROB = 24;          // 8 batches x {xy, xx, yy}
constexpr int WGS_PER_PROB = 64;   // 32 rows per WG -> grid 1536 = 6 WG/CU
constexpr int THREADS = 256;       // 8 row-groups x 32 source-chunks
constexpr int CHUNKS = 32;
constexpr int RPT = 4;             // rows per thread (register tile)
constexpr int NPASS = 100;         // 50 Sinkhorn iters x 2 half-passes
constexpr int STAGE = 1024;        // points per LDS stage (16 KB)
constexpr float KS = 1.44269504088896340736f / 0.0025f;           // log2e/eps
constexpr float NEG_EPS_LN2 = -0.0025f * 0.69314718055994530942f; // -eps*ln2
constexpr float LOG2N = 11.0f;                                    // log2(2048)
}

// One half-pass (SEPARATE launch per pass — graph replay showed ~zero gap;
// cooperative launch at grid 1536 is rejected by this driver, rounds 4/5).
// For each target row i:
//   out_i = -eps*( ln(sum_j exp((phi_j - C_ij)/eps)) - ln(2048) )
// base-2: w_ij = KS*t_i.s_j + A_j (+ Bi folded at the end),
//   A_j = KS*phi_j - 0.5*KS*|s_j|^2, Bi = -0.5*KS*|t_i|^2.
// __launch_bounds__(256,8): 64-VGPR cap (kernel needs ~48) + 16 KB LDS ->
// up to 8 WG/CU; grid 1536 gives 6 WG/CU = 24 waves to overlap the
// LDS -> VALU -> exp -> VALU dependent chain across pipes.
__global__ void __launch_bounds__(THREADS, 8) sink_halfpass(
    const float* __restrict__ p1, const float* __restrict__ p2,
    float* __restrict__ fpot, float* __restrict__ gpot, int t)
{
  __shared__ float4 Ls[STAGE];   // (KS*sx, KS*sy, KS*sz, A_j), 16 KB

  const int w   = blockIdx.x;
  const int p   = w >> 6;          // problem 0..23
  const int blk = w & 63;          // row-block within problem
  const int b    = p / 3;
  const int kind = p - 3 * b;      // 0: xy, 1: xx, 2: yy
  const float* X = (kind == 2 ? p2 : p1) + b * (NPTS * 3);
  const float* Y = (kind == 1 ? p1 : p2) + b * (NPTS * 3);
  const bool even = (t & 1) == 0;
  const float* tgt = even ? X : Y;       // even: f-update (rows of X)
  const float* src = even ? Y : X;
  const float* phi = (even ? gpot : fpot) + p * NPTS;
  float*      outp = (even ? fpot : gpot) + p * NPTS;

  const int tid = threadIdx.x;
  const int c  = tid & (CHUNKS - 1);       // source chunk 0..31
  const int rg = tid >> 5;                 // row group 0..7
  const int row0 = blk * 32 + rg * RPT;

  float tx0 = tgt[3 * (row0 + 0) + 0], ty0 = tgt[3 * (row0 + 0) + 1], tz0 = tgt[3 * (row0 + 0) + 2];
  float tx1 = tgt[3 * (row0 + 1) + 0], ty1 = tgt[3 * (row0 + 1) + 1], tz1 = tgt[3 * (row0 + 1) + 2];
  float tx2 = tgt[3 * (row0 + 2) + 0], ty2 = tgt[3 * (row0 + 2) + 1], tz2 = tgt[3 * (row0 + 2) + 2];
  float tx3 = tgt[3 * (row0 + 3) + 0], ty3 = tgt[3 * (row0 + 3) + 1], tz3 = tgt[3 * (row0 + 3) + 2];

  float mb0 = -1e30f, mb1 = -1e30f, mb2 = -1e30f, mb3 = -1e30f;
  float s0 = 0.f, s1 = 0.f, s2 = 0.f, s3 = 0.f;

  // Quad-of-sources online LSE for one row (math bit-identical to round 2/3,
  // which validated absmax 0.0)
#define QSTEP(tx, ty, tz, mb, ss) {                                          \
    float u0_ = fmaf(tx, L0.x, fmaf(ty, L0.y, fmaf(tz, L0.z, L0.w)));        \
    float u1_ = fmaf(tx, L1.x, fmaf(ty, L1.y, fmaf(tz, L1.z, L1.w)));        \
    float u2_ = fmaf(tx, L2.x, fmaf(ty, L2.y, fmaf(tz, L2.z, L2.w)));        \
    float u3_ = fmaf(tx, L3.x, fmaf(ty, L3.y, fmaf(tz, L3.z, L3.w)));        \
    float m_  = fmaxf(fmaxf(u0_, u1_), fmaxf(u2_, u3_));                     \
    float es_ = (fexp2(u0_ - m_) + fexp2(u1_ - m_))                          \
              + (fexp2(u2_ - m_) + fexp2(u3_ - m_));                         \
    float mo_ = fmaxf(mb, m_);                                               \
    (ss) = fmaf((ss), fexp2((mb) - mo_), es_ * fexp2(m_ - mo_));             \
    (mb) = mo_; }

  // Two 1024-point LDS stages; online state carries across stages.
  #pragma unroll
  for (int st = 0; st < 2; ++st) {
    __syncthreads();   // stage-0: no-op hazard-wise; stage-1: readers done
    #pragma unroll
    for (int i = 0; i < STAGE / THREADS; ++i) {
      int jl = tid + THREADS * i;
      int j  = st * STAGE + jl;
      float sx = src[3 * j + 0], sy = src[3 * j + 1], sz = src[3 * j + 2];
      float ph = (t == 0) ? 0.0f : phi[j];   // plain load: kernel-boundary coherent
      float A = fmaf(KS, ph, -0.5f * KS * (sx * sx + sy * sy + sz * sz));
      Ls[jl] = make_float4(KS * sx, KS * sy, KS * sz, A);
    }
    __syncthreads();

    const float4* Lp = Ls + c;
    #pragma unroll 2
    for (int q = 0; q < STAGE / (CHUNKS * 4); ++q) {   // 8 quads
      const float4* Lq = Lp + 128 * q;    // j_local = 32*(4q+k) + c
      float4 L0 = Lq[0];
      float4 L1 = Lq[32];
      float4 L2 = Lq[64];
      float4 L3 = Lq[96];
      QSTEP(tx0, ty0, tz0, mb0, s0);
      QSTEP(tx1, ty1, tz1, mb1, s1);
      QSTEP(tx2, ty2, tz2, mb2, s2);
      QSTEP(tx3, ty3, tz3, mb3, s3);
    }
  }
#undef QSTEP

  // ---- merge the 32 chunk lanes (butterfly within 32-lane halves; each
  // half-wave has uniform rg, c = lane&31) ----
#define LMERGE(mb, ss) {                                                     \
    float Mo_ = __shfl_xor((mb), off);                                       \
    float So_ = __shfl_xor((ss), off);                                       \
    float mo_ = fmaxf((mb), Mo_);                                            \
    (ss) = fmaf((ss), fexp2((mb) - mo_), So_ * fexp2(Mo_ - mo_));            \
    (mb) = mo_; }

  #pragma unroll
  for (int off = 1; off <= 16; off <<= 1) {
    LMERGE(mb0, s0);
    LMERGE(mb1, s1);
    LMERGE(mb2, s2);
    LMERGE(mb3, s3);
  }
#undef LMERGE

  if (c == 0) {
    float B0 = -0.5f * KS * (tx0 * tx0 + ty0 * ty0 + tz0 * tz0);
    float B1 = -0.5f * KS * (tx1 * tx1 + ty1 * ty1 + tz1 * tz1);
    float B2 = -0.5f * KS * (tx2 * tx2 + ty2 * ty2 + tz2 * tz2);
    float B3 = -0.5f * KS * (tx3 * tx3 + ty3 * ty3 + tz3 * tz3);
    outp[row0 + 0] = NEG_EPS_LN2 * (mb0 + B0 + flog2(s0) - LOG2N);
    outp[row0 + 1] = NEG_EPS_LN2 * (mb1 + B1 + flog2(s1) - LOG2N);
    outp[row0 + 2] = NEG_EPS_LN2 * (mb2 + B2 + flog2(s2) - LOG2N);
    outp[row0 + 3] = NEG_EPS_LN2 * (mb3 + B3 + flog2(s3) - LOG2N);
  }
}

// 48-WG partial reduction: block b covers 2048 floats of [fpot|gpot] flat.
// weight = (problem%3==0 ? 1 : -0.5); final division happens in sink_final.
__global__ void __launch_bounds__(THREADS) sink_partial(
    const float* __restrict__ pot, double* __restrict__ partial)
{
  __shared__ double red[THREADS];
  const int bId = blockIdx.x;                 // 0..47
  const int prob = bId % NPROB;
  const double wgt = (prob % 3 == 0) ? 1.0 : -0.5;
  const float4* p4 = (const float4*)(pot + bId * NPTS);
  const int tid = threadIdx.x;
  float4 v0 = p4[tid];
  float4 v1 = p4[tid + THREADS];
  double acc = ((double)v0.x + (double)v0.y) + ((double)v0.z + (double)v0.w)
             + ((double)v1.x + (double)v1.y) + ((double)v1.z + (double)v1.w);
  red[tid] = acc;
  __syncthreads();
  for (int st = THREADS / 2; st > 0; st >>= 1) {
    if (tid < st) red[tid] += red[tid + st];
    __syncthreads();
  }
  if (tid == 0) partial[bId] = wgt * red[0];
}

__global__ void __launch_bounds__(64) sink_final(
    const double* __restrict__ partial, float* __restrict__ out)
{
  const int tid = threadIdx.x;
  double v = (tid < 48) ? partial[tid] : 0.0;
  for (int off = 32; off > 0; off >>= 1) v += __shfl_down(v, off);
  if (tid == 0) out[0] = (float)(v / (8.0 * 2048.0));
}

extern "C" void kernel_launch(void* const* d_in, const int* in_sizes, int n_in,
                              void* d_out, int out_size, void* d_ws, size_t ws_size,
                              hipStream_t stream)
{
  const float* p1 = (const float*)d_in[0];   // pcs1 [8,2048,3] f32
  const float* p2 = (const float*)d_in[1];   // pcs2 [8,2048,3] f32
  float* fpot = (float*)d_ws;                // [24][2048]
  float* gpot = fpot + NPROB * NPTS;         // [24][2048] (contiguous)
  double* partial = (double*)(gpot + NPROB * NPTS);  // [48], 8B-aligned
                                             // total ws use: 384.4 KB (< round-3's proven footprint)

  for (int t = 0; t < NPASS; ++t) {
    sink_halfpass<<<dim3(NPROB * WGS_PER_PROB), dim3(THREADS), 0, stream>>>(
        p1, p2, fpot, gpot, t);
  }
  sink_partial<<<dim3(2 * NPROB), dim3(THREADS), 0, stream>>>(fpot, partial);
  sink_final<<<dim3(1), dim3(64), 0, stream>>>(partial, (float*)d_out);
}